// Round 1
// baseline (29.671 us; speedup 1.0000x reference)
//
#include <hip/hip_runtime.h>
#include <math.h>

// Problem constants (from reference):
//   N=4096, P=4  -> B = 16384 rows
//   SMK = 567 (signal length), L = 8 (taps), OUTLEN = SMK+L-1 = 574
//   M = 64 (DFT size)
// Output layout (flat, concatenated in return order):
//   out:    (B, 574, 2) float32   = 18,808,832 elems
//   H_true: (B,  64, 2) float32   =  2,097,152 elems

#define B_ROWS 16384
#define SMK    567
#define LTAPS  8
#define OUTLEN 574
#define MFFT   64

__global__ __launch_bounds__(256) void channel_kernel(
    const float2* __restrict__ x,    // (B, SMK)  complex as float2
    const float2* __restrict__ cof,  // (B, LTAPS) complex as float2
    float2* __restrict__ out,        // (B, OUTLEN)
    float2* __restrict__ H)          // (B, MFFT)
{
    // Padded signal: xs[i+7] = x[i] for i in [0,566]; xs[0..6] and xs[574..580] = 0.
    // Then out[i] = sum_{j=0..7} h[j] * xs[i - j + 7], no bounds checks needed.
    __shared__ float2 xs[OUTLEN + LTAPS - 1];  // 581 entries, ~4.6 KB

    const int b   = blockIdx.x;
    const int tid = threadIdx.x;

    const float2* __restrict__ xrow = x + (size_t)b * SMK;

    // Zero the 14 pad slots (7 front, 7 back).
    if (tid < 2 * (LTAPS - 1)) {
        int idx = (tid < LTAPS - 1) ? tid : (OUTLEN + tid - (LTAPS - 1));
        xs[idx] = make_float2(0.0f, 0.0f);
    }
    // Stage the row (coalesced 8B loads).
    for (int i = tid; i < SMK; i += 256) {
        xs[i + (LTAPS - 1)] = xrow[i];
    }

    // Taps -> registers (16 floats, broadcast-friendly; cof is L2-resident ~1MB).
    const float2* __restrict__ crow = cof + (size_t)b * LTAPS;
    float2 h[LTAPS];
    #pragma unroll
    for (int j = 0; j < LTAPS; ++j) h[j] = crow[j];

    __syncthreads();

    // FIR: each thread does up to 3 outputs (574 / 256).
    float2* __restrict__ orow = out + (size_t)b * OUTLEN;
    #pragma unroll
    for (int it = 0; it < 3; ++it) {
        int i = tid + it * 256;
        if (i < OUTLEN) {
            float sr = 0.0f, si = 0.0f;
            #pragma unroll
            for (int j = 0; j < LTAPS; ++j) {
                float2 xv = xs[i - j + (LTAPS - 1)];
                sr = fmaf(h[j].x, xv.x, sr);
                sr = fmaf(-h[j].y, xv.y, sr);
                si = fmaf(h[j].x, xv.y, si);
                si = fmaf(h[j].y, xv.x, si);
            }
            orow[i] = make_float2(sr, si);
        }
    }

    // 64-point DFT of the 8 taps: H[k] = sum_l h[l] * e^{-2*pi*i*k*l/64}.
    // Threads 0..63 (first wave) each own one k.
    if (tid < MFFT) {
        const int k = tid;
        float accr = 0.0f, acci = 0.0f;
        #pragma unroll
        for (int l = 0; l < LTAPS; ++l) {
            // reduce k*l mod 64 for precision; ang = -2*pi*t/64
            int t = (k * l) & (MFFT - 1);
            float ang = -6.2831853071795864769f * (float)t * (1.0f / (float)MFFT);
            float s, c;
            __sincosf(ang, &s, &c);
            // (hr + i*hi) * (c + i*s): re = hr*c - hi*s, im = hr*s + hi*c
            accr = fmaf(h[l].x, c, accr);
            accr = fmaf(-h[l].y, s, accr);
            acci = fmaf(h[l].x, s, acci);
            acci = fmaf(h[l].y, c, acci);
        }
        H[(size_t)b * MFFT + k] = make_float2(accr, acci);
    }
}

extern "C" void kernel_launch(void* const* d_in, const int* in_sizes, int n_in,
                              void* d_out, int out_size, void* d_ws, size_t ws_size,
                              hipStream_t stream) {
    const float2* x   = (const float2*)d_in[0];  // (N,P,SMK,2) f32
    const float2* cof = (const float2*)d_in[1];  // (N,P,L,2)  f32
    float* outf = (float*)d_out;

    float2* conv_out = (float2*)outf;                                  // (B, 574)
    float2* H        = (float2*)(outf + (size_t)B_ROWS * OUTLEN * 2);  // (B, 64)

    channel_kernel<<<B_ROWS, 256, 0, stream>>>(x, cof, conv_out, H);
}